// Round 11
// baseline (220.563 us; speedup 1.0000x reference)
//
#include <hip/hip_runtime.h>

// SimpleConcatAttention on MI355X — round 11: keyT deleted; phase-4 stages f32 key
// with in-register transpose-convert. prep = qW GEMM only.
// Inputs: query f32 [512,1024], key f32 [16,2048,1024], W f32 [1024,1024],
// att_mask int32 [16,512,2048]. Outputs (d_out, f32): out [16,512,1024] ++ att [16,512,2048].
// Pipeline (main path, ws >= 34 MiB):
//   prep_qw:  qW=(q@W)/32 (3-MFMA fp16, 64x64, BK=64) -> qW_h/qW_l planes (128 blocks)
//   phase2:   att_raw = qW @ key^T (2-MFMA; B = f32 key staged via global_load_lds,
//             16B-granule XOR, fp16 convert at frag read) — r10-verified, 80us
//   softmax:  masked softmax in place (coalesced int4 mask), emits att_h fp16
//   phase4:   out = att_h @ key (gemm_av): A = att_h via global_load_lds BK=128
//             (verified octet-XOR); B = f32 key, reg-staged transpose-convert:
//             thread owns 4d x 8k block, 8x f32x4 coalesced loads -> 4x u16x8
//             LDS writes at d*128+((oct^(d&7))<<3). Derived banks: write start
//             4*(oct^(d&7)) uniform-ish (~2x writes only); frag reads = verified
//             0-conflict pattern. Kills keyT (r10 lesson: every materialized
//             conversion buffer lost once producer traffic was counted).
// Fallback (small ws): verified round-1 all-f32-input bf16-split path.

typedef float  f32x4  __attribute__((ext_vector_type(4)));
typedef short  bf16x8 __attribute__((ext_vector_type(8)));
typedef _Float16 f16x8 __attribute__((ext_vector_type(8)));
typedef unsigned short u16;
typedef unsigned short u16x8 __attribute__((ext_vector_type(8)));
typedef unsigned short u16x4 __attribute__((ext_vector_type(4)));

// ---- fp16 split: x = hi + lo, |x-hi-lo| <= 2^-22 |x| ----
__device__ __forceinline__ void split2h(float x, u16& hi, u16& lo)
{
    _Float16 h = (_Float16)x;
    _Float16 l = (_Float16)(x - (float)h);
    hi = __builtin_bit_cast(u16, h);
    lo = __builtin_bit_cast(u16, l);
}

// ---- bf16 split (fallback path) ----
__device__ __forceinline__ void split2(float x, u16& hi, u16& lo)
{
    unsigned u = __float_as_uint(x);
    hi = (u16)(u >> 16);
    float hf = __uint_as_float(u & 0xFFFF0000u);
    float lf = x - hf;
    lo = (u16)(__float_as_uint(lf) >> 16);
}

__device__ __forceinline__ void async_cp16(const void* g, void* l)
{
    __builtin_amdgcn_global_load_lds(
        (const __attribute__((address_space(1))) unsigned int*)g,
        (__attribute__((address_space(3))) unsigned int*)l, 16, 0, 0);
}

// ---------------------------------------------------------------------------
// Phase-2 scores GEMM: att[z] = qW @ key[z]^T.  (r10-verified, unchanged)
// A: qW_h/qW_l fp16 planes [512][1024]; B: key f32 [z][2048][1024].
// 128x128 tile, BK=64, 4 waves 2x2. 2-MFMA: Ah.B + Al.B (B = fp16(key)).
// ---------------------------------------------------------------------------
__global__ __launch_bounds__(256, 2) void gemm_s(
    const u16* __restrict__ Ah, const u16* __restrict__ Al,
    const float* __restrict__ key, float* __restrict__ C)
{
    __shared__ __attribute__((aligned(16))) unsigned char smem[65536];
    u16*   Ahs = (u16*)smem;                      // [128][64] u16, 16KB
    u16*   Als = (u16*)(smem + 16384);            // 16KB
    float* Bfs = (float*)(smem + 32768);          // [128][64] f32, 32KB

    const int tid  = threadIdx.x;
    const int lane = tid & 63;
    const int wid  = tid >> 6;
    const int wm   = wid >> 1, wn = wid & 1;      // 2x2 wave grid, 64x64 each
    const int fr   = lane & 15;                   // frag row/col
    const int fq   = lane >> 4;                   // k-quarter

    const int m0 = blockIdx.y * 128, n0 = blockIdx.x * 128;
    const u16*   Ag  = Ah + (long)m0 * 1024;
    const u16*   Ag2 = Al + (long)m0 * 1024;
    const float* Bg  = key + (long)blockIdx.z * 2048 * 1024 + (long)n0 * 1024;

    f32x4 acc[4][4];
#pragma unroll
    for (int i = 0; i < 4; i++)
#pragma unroll
        for (int j = 0; j < 4; j++) acc[i][j] = (f32x4){0.f, 0.f, 0.f, 0.f};

    for (int k0 = 0; k0 < 1024; k0 += 64) {
        __syncthreads();                          // prev tile's frag reads done
        // ---- A staging (u16 planes): 16 chunks each, octet-XOR (r&7) ----
#pragma unroll
        for (int i = 0; i < 4; i++) {
            const int q   = wid * 4 + i;
            const int p   = q * 512 + lane * 8;   // flat u16 pos
            const int r   = p >> 6;               // row
            const int oct = (p & 63) >> 3;
            const long go = (long)r * 1024 + k0 + ((oct ^ (r & 7)) << 3);
            async_cp16(Ag + go, Ahs + q * 512);
            async_cp16(Ag2 + go, Als + q * 512);
        }
        // ---- B staging (f32): 32 chunks, 16B-granule XOR (r&15) ----
#pragma unroll
        for (int i = 0; i < 8; i++) {
            const int q = wid * 8 + i;
            const int G = q * 64 + lane;          // flat 16B-granule index
            const int r = G >> 4;                 // row (128 rows x 16 granules)
            const int g = G & 15;
            const long go = (long)r * 1024 + k0 + ((g ^ (r & 15)) << 2);
            async_cp16(Bg + go, Bfs + q * 256);
        }
        __syncthreads();                          // compiler drains vmcnt

        // ---- 2 k-steps of 32: frag reads (swizzled) + MFMAs ----
#pragma unroll
        for (int ks = 0; ks < 2; ks++) {
            const int cl = fq + ks * 4;           // 8-elem octet index 0..7
            f16x8 ah[4], al[4], bh[4];
#pragma unroll
            for (int i = 0; i < 4; i++) {
                const int ra = wm * 64 + i * 16 + fr;
                const int oa = ra * 64 + ((cl ^ (ra & 7)) << 3);
                ah[i] = *(const f16x8*)&Ahs[oa];
                al[i] = *(const f16x8*)&Als[oa];
                const int rb = wn * 64 + i * 16 + fr;
                const int g0 = ((2 * cl)     ^ (rb & 15)) << 2;   // f32 col of k..k+3
                const int g1 = ((2 * cl + 1) ^ (rb & 15)) << 2;   // f32 col of k+4..k+7
                f32x4 b0 = *(const f32x4*)&Bfs[rb * 64 + g0];
                f32x4 b1 = *(const f32x4*)&Bfs[rb * 64 + g1];
#pragma unroll
                for (int e = 0; e < 4; e++) {
                    bh[i][e]     = (_Float16)b0[e];
                    bh[i][4 + e] = (_Float16)b1[e];
                }
            }
#pragma unroll
            for (int i = 0; i < 4; i++)
#pragma unroll
                for (int j = 0; j < 4; j++) {
                    acc[i][j] = __builtin_amdgcn_mfma_f32_16x16x32_f16(ah[i], bh[j], acc[i][j], 0, 0, 0);
                    acc[i][j] = __builtin_amdgcn_mfma_f32_16x16x32_f16(al[i], bh[j], acc[i][j], 0, 0, 0);
                }
        }
    }

    // ---- epilogue (m89 layout: row = fq*4 + q, col = fr) ----
    float* Cg = C + (long)blockIdx.z * 512 * 2048 + (long)(m0 + wm * 64) * 2048 + (n0 + wn * 64);
    const int r4 = fq * 4;
#pragma unroll
    for (int i = 0; i < 4; i++)
#pragma unroll
        for (int j = 0; j < 4; j++) {
            float* cp = Cg + (long)(i * 16 + r4) * 2048 + j * 16 + fr;
#pragma unroll
            for (int q = 0; q < 4; q++)
                cp[(long)q * 2048] = acc[i][j][q];
        }
}

// ---------------------------------------------------------------------------
// Phase-4: out[z] = att_h[z] @ key[z]   (gemm_av)
// A: att_h fp16 [512][2048] via global_load_lds (BK=128, verified octet-XOR).
// B: key f32 [2048][1024], reg-staged transpose-convert to LDS [d][k'] fp16.
// 128x128 tile, 4 waves 2x2, 1-MFMA.
// ---------------------------------------------------------------------------
__global__ __launch_bounds__(256, 2) void gemm_av(
    const u16* __restrict__ Ah, const float* __restrict__ key,
    float* __restrict__ C)
{
    constexpr int BK = 128;
    __shared__ __attribute__((aligned(16))) u16 lds[2 * 128 * BK];  // 64 KB
    u16* Ahs = lds;                               // A plane [128 m][128 k]
    u16* Bhs = lds + 128 * BK;                    // B plane [128 d][128 k]

    const int tid  = threadIdx.x;
    const int lane = tid & 63;
    const int wid  = tid >> 6;
    const int wm   = wid >> 1, wn = wid & 1;
    const int fr   = lane & 15;
    const int fq   = lane >> 4;

    const int m0 = blockIdx.y * 128, n0 = blockIdx.x * 128;
    const u16*   Ag = Ah + (long)blockIdx.z * 512 * 2048 + (long)m0 * 2048;
    const float* Bg = key + (long)blockIdx.z * 2048 * 1024 + n0;

    f32x4 acc[4][4];
#pragma unroll
    for (int i = 0; i < 4; i++)
#pragma unroll
        for (int j = 0; j < 4; j++) acc[i][j] = (f32x4){0.f, 0.f, 0.f, 0.f};

    for (int k0 = 0; k0 < 2048; k0 += BK) {
        __syncthreads();                          // prev tile's frag reads done
        // ---- A staging: 32 chunks of 1KB, octet-XOR (r&7) (verified) ----
#pragma unroll
        for (int i = 0; i < 8; i++) {
            const int q   = wid * 8 + i;
            const int p   = q * 512 + lane * 8;
            const int r   = p >> 7;               // row 0..127
            const int oct = (p & 127) >> 3;       // 0..15
            const long go = (long)r * 2048 + k0 + ((oct ^ (r & 7)) << 3);
            async_cp16(Ag + go, Ahs + q * 512);
        }
        // ---- B staging: transpose-convert key[k0+k'][n0+d] -> Bhs[d][k'] ----
        // pair p: oct = p>>5 (k'-octet 0..15), d4 = (p&31)*4. 8x f32x4 coalesced
        // loads (32 lanes x 16B = 512B/row-segment), 4x u16x8 swizzled writes.
#pragma unroll
        for (int i = 0; i < 2; i++) {
            const int p   = tid + i * 256;        // 512 pairs
            const int oct = p >> 5;               // 0..15
            const int d4  = (p & 31) * 4;
            f32x4 v[8];
#pragma unroll
            for (int j = 0; j < 8; j++)
                v[j] = *(const f32x4*)(Bg + (long)(k0 + oct * 8 + j) * 1024 + d4);
#pragma unroll
            for (int e = 0; e < 4; e++) {
                const int d = d4 + e;
                u16x8 hv;
#pragma unroll
                for (int j = 0; j < 8; j++) {
                    _Float16 h = (_Float16)v[j][e];
                    hv[j] = __builtin_bit_cast(u16, h);
                }
                *(u16x8*)&Bhs[d * BK + ((oct ^ (d & 7)) << 3)] = hv;
            }
        }
        __syncthreads();                          // drains vmcnt + lgkmcnt

        // ---- 4 k-steps of 32: frag reads (verified pattern) + MFMAs ----
#pragma unroll
        for (int ks = 0; ks < 4; ks++) {
            const int cl = fq + ks * 4;           // 0..15
            f16x8 ah[4], bh[4];
#pragma unroll
            for (int i = 0; i < 4; i++) {
                const int ra = wm * 64 + i * 16 + fr;
                ah[i] = *(const f16x8*)&Ahs[ra * BK + ((cl ^ (ra & 7)) << 3)];
                const int rb = wn * 64 + i * 16 + fr;
                bh[i] = *(const f16x8*)&Bhs[rb * BK + ((cl ^ (rb & 7)) << 3)];
            }
#pragma unroll
            for (int i = 0; i < 4; i++)
#pragma unroll
                for (int j = 0; j < 4; j++)
                    acc[i][j] = __builtin_amdgcn_mfma_f32_16x16x32_f16(ah[i], bh[j], acc[i][j], 0, 0, 0);
        }
    }

    // ---- epilogue (m89 layout) ----
    float* Cg = C + (long)blockIdx.z * 512 * 1024 + (long)(m0 + wm * 64) * 1024 + (n0 + wn * 64);
    const int r4 = fq * 4;
#pragma unroll
    for (int i = 0; i < 4; i++)
#pragma unroll
        for (int j = 0; j < 4; j++) {
            float* cp = Cg + (long)(i * 16 + r4) * 1024 + j * 16 + fr;
#pragma unroll
            for (int q = 0; q < 4; q++)
                cp[(long)q * 1024] = acc[i][j][q];
        }
}

// ---------------------------------------------------------------------------
// prep_qw: qW = (query @ W)/32 (NN, 3-MFMA fp16 in-kernel split),
// 64x64 tile, BK=64 (16 iters), 128 blocks -> qW_h/qW_l fp16 planes.
// (r7-verified GEMM role, streaming role removed.)
// ---------------------------------------------------------------------------
__global__ __launch_bounds__(256) void prep_qw(
    const float* __restrict__ query, const float* __restrict__ W,
    u16* __restrict__ qW_h, u16* __restrict__ qW_l)
{
    constexpr int LDg = 72;                       // LDS row stride (u16)
    __shared__ __attribute__((aligned(16))) u16 sm[4 * 64 * LDg];   // 36 KiB
    const int tid = threadIdx.x;

    u16* As_h = sm;                               // [64][72]
    u16* As_l = sm + 64 * LDg;
    u16* Bs_h = sm + 2 * 64 * LDg;
    u16* Bs_l = sm + 3 * 64 * LDg;

    const int lane = tid & 63, wid = tid >> 6;
    const int wm = wid >> 1, wn = wid & 1;        // 2x2 wave grid, 32x32 each
    const int lr = lane & 15, fq = lane >> 4;
    const int m0 = ((int)blockIdx.x >> 4) * 64;   // 8 m-tiles
    const int n0 = ((int)blockIdx.x & 15) * 64;   // 16 n-tiles
    const float* Ag = query + (long)m0 * 1024;
    const float* Bg = W + n0;

    f32x4 acc[2][2];
#pragma unroll
    for (int i = 0; i < 2; i++)
#pragma unroll
        for (int j = 0; j < 2; j++) acc[i][j] = (f32x4){0.f, 0.f, 0.f, 0.f};

    for (int k0 = 0; k0 < 1024; k0 += 64) {
        __syncthreads();
        // stage A [64 m x 64 k]
        {
            const int row = tid >> 2, kb = (tid & 3) * 16;
            const float* src = Ag + (long)row * 1024 + k0 + kb;
            f32x4 v0 = *(const f32x4*)src;
            f32x4 v1 = *(const f32x4*)(src + 4);
            f32x4 v2 = *(const f32x4*)(src + 8);
            f32x4 v3 = *(const f32x4*)(src + 12);
            u16x8 h0, h1, l0, l1;
#pragma unroll
            for (int e = 0; e < 4; e++) {
                u16 hh, ll;
                split2h(v0[e], hh, ll); h0[e] = hh;     l0[e] = ll;
                split2h(v1[e], hh, ll); h0[4 + e] = hh; l0[4 + e] = ll;
                split2h(v2[e], hh, ll); h1[e] = hh;     l1[e] = ll;
                split2h(v3[e], hh, ll); h1[4 + e] = hh; l1[4 + e] = ll;
            }
            *(u16x8*)&As_h[row * LDg + kb]     = h0;
            *(u16x8*)&As_h[row * LDg + kb + 8] = h1;
            *(u16x8*)&As_l[row * LDg + kb]     = l0;
            *(u16x8*)&As_l[row * LDg + kb + 8] = l1;
        }
        // stage B (W[k][n] 64x64, transpose in regs)
        {
            const int n = lane;
            u16x8 h0, h1, l0, l1;
#pragma unroll
            for (int kk = 0; kk < 8; kk++) {
                float x0 = Bg[(long)(k0 + wid * 16 + kk) * 1024 + n];
                float x1 = Bg[(long)(k0 + wid * 16 + 8 + kk) * 1024 + n];
                u16 hh, ll;
                split2h(x0, hh, ll); h0[kk] = hh; l0[kk] = ll;
                split2h(x1, hh, ll); h1[kk] = hh; l1[kk] = ll;
            }
            *(u16x8*)&Bs_h[n * LDg + wid * 16]     = h0;
            *(u16x8*)&Bs_h[n * LDg + wid * 16 + 8] = h1;
            *(u16x8*)&Bs_l[n * LDg + wid * 16]     = l0;
            *(u16x8*)&Bs_l[n * LDg + wid * 16 + 8] = l1;
        }
        __syncthreads();

#pragma unroll
        for (int ks = 0; ks < 2; ks++) {
            f16x8 ah[2], al[2], bh[2], bl[2];
#pragma unroll
            for (int i = 0; i < 2; i++) {
                const int ra = (wm * 32 + i * 16 + lr) * LDg + ks * 32 + fq * 8;
                ah[i] = *(const f16x8*)&As_h[ra];
                al[i] = *(const f16x8*)&As_l[ra];
                const int rb = (wn * 32 + i * 16 + lr) * LDg + ks * 32 + fq * 8;
                bh[i] = *(const f16x8*)&Bs_h[rb];
                bl[i] = *(const f16x8*)&Bs_l[rb];
            }
#pragma unroll
            for (int i = 0; i < 2; i++)
#pragma unroll
                for (int j = 0; j < 2; j++) {
                    acc[i][j] = __builtin_amdgcn_mfma_f32_16x16x32_f16(ah[i], bh[j], acc[i][j], 0, 0, 0);
                    acc[i][j] = __builtin_amdgcn_mfma_f32_16x16x32_f16(ah[i], bl[j], acc[i][j], 0, 0, 0);
                    acc[i][j] = __builtin_amdgcn_mfma_f32_16x16x32_f16(al[i], bh[j], acc[i][j], 0, 0, 0);
                }
        }
    }

    // epilogue: scale + split -> fp16 planes
    const int r4 = fq * 4;
#pragma unroll
    for (int i = 0; i < 2; i++)
#pragma unroll
        for (int j = 0; j < 2; j++)
#pragma unroll
            for (int q = 0; q < 4; q++) {
                float v = acc[i][j][q] * (1.f / 32.f);
                u16 hh, ll;
                split2h(v, hh, ll);
                const long o = (long)(m0 + wm * 32 + i * 16 + r4 + q) * 1024
                             + n0 + wn * 32 + j * 16 + lr;
                qW_h[o] = hh;
                qW_l[o] = ll;
            }
}

// ---------------------------------------------------------------------------
// Round-1 f32 MFMA GEMM (fallback path only).
// ---------------------------------------------------------------------------
template<bool BT>
__global__ __launch_bounds__(256, 2) void gemm_mfma(
    const float* __restrict__ A, const float* __restrict__ B,
    float* __restrict__ C,
    int Kd, int lda, int ldb, int ldc,
    long sA, long sB, long sC, float scale)
{
    constexpr int LD = 40;
    __shared__ __attribute__((aligned(16))) u16 As_hi[128 * LD];
    __shared__ __attribute__((aligned(16))) u16 As_lo[128 * LD];
    __shared__ __attribute__((aligned(16))) u16 Bs_hi[128 * LD];
    __shared__ __attribute__((aligned(16))) u16 Bs_lo[128 * LD];

    const int tid  = threadIdx.x;
    const int lane = tid & 63;
    const int wid  = tid >> 6;
    const int wm   = wid >> 1, wn = wid & 1;
    const int lr   = lane & 15;
    const int lk   = (lane >> 4) * 8;

    const int m0 = blockIdx.y * 128, n0 = blockIdx.x * 128;
    const float* Ag = A + (long)blockIdx.z * sA + (long)m0 * lda;
    const float* Bg = B + (long)blockIdx.z * sB + (BT ? (long)n0 * ldb : (long)n0);

    f32x4 acc[4][4];
#pragma unroll
    for (int i = 0; i < 4; i++)
#pragma unroll
        for (int j = 0; j < 4; j++) acc[i][j] = (f32x4){0.f, 0.f, 0.f, 0.f};

    for (int k0 = 0; k0 < Kd; k0 += 32) {
        __syncthreads();
#pragma unroll
        for (int it = 0; it < 2; it++) {
            const int p   = tid + it * 256;
            const int row = p >> 2, k8 = (p & 3) * 8;
            const float* src = Ag + (long)row * lda + k0 + k8;
            f32x4 v0 = *(const f32x4*)src;
            f32x4 v1 = *(const f32x4*)(src + 4);
            u16x8 h, l;
#pragma unroll
            for (int e = 0; e < 4; e++) {
                u16 hh, ll;
                split2(v0[e], hh, ll); h[e] = hh;     l[e] = ll;
                split2(v1[e], hh, ll); h[4 + e] = hh; l[4 + e] = ll;
            }
            *(u16x8*)&As_hi[row * LD + k8] = h;
            *(u16x8*)&As_lo[row * LD + k8] = l;
        }
        if constexpr (BT) {
#pragma unroll
            for (int it = 0; it < 2; it++) {
                const int p   = tid + it * 256;
                const int row = p >> 2, k8 = (p & 3) * 8;
                const float* src = Bg + (long)row * ldb + k0 + k8;
                f32x4 v0 = *(const f32x4*)src;
                f32x4 v1 = *(const f32x4*)(src + 4);
                u16x8 h, l;
#pragma unroll
                for (int e = 0; e < 4; e++) {
                    u16 hh, ll;
                    split2(v0[e], hh, ll); h[e] = hh;     l[e] = ll;
                    split2(v1[e], hh, ll); h[4 + e] = hh; l[4 + e] = ll;
                }
                *(u16x8*)&Bs_hi[row * LD + k8] = h;
                *(u16x8*)&Bs_lo[row * LD + k8] = l;
            }
        } else {
#pragma unroll
            for (int h2 = 0; h2 < 2; h2++) {
                const int n = h2 * 64 + lane;
                u16x8 h, l;
#pragma unroll
                for (int kk = 0; kk < 8; kk++) {
                    float x = Bg[(long)(k0 + wid * 8 + kk) * ldb + n];
                    u16 hh, ll;
                    split2(x, hh, ll);
                    h[kk] = hh; l[kk] = ll;
                }
                *(u16x8*)&Bs_hi[n * LD + wid * 8] = h;
                *(u16x8*)&Bs_lo[n * LD + wid * 8] = l;
            }
        }
        __syncthreads();

        bf16x8 ah[4], al[4], bh[4], bl[4];
#pragma unroll
        for (int i = 0; i < 4; i++) {
            const int ra = (wm * 64 + i * 16 + lr) * LD + lk;
            ah[i] = *(const bf16x8*)&As_hi[ra];
            al[i] = *(const bf16x8*)&As_lo[ra];
            const int rb = (wn * 64 + i * 16 + lr) * LD + lk;
            bh[i] = *(const bf16x8*)&Bs_hi[rb];
            bl[i] = *(const bf16x8*)&Bs_lo[rb];
        }
#pragma unroll
        for (int i = 0; i < 4; i++)
#pragma unroll
            for (int j = 0; j < 4; j++) {
                acc[i][j] = __builtin_amdgcn_mfma_f32_16x16x32_bf16(ah[i], bh[j], acc[i][j], 0, 0, 0);
                acc[i][j] = __builtin_amdgcn_mfma_f32_16x16x32_bf16(ah[i], bl[j], acc[i][j], 0, 0, 0);
                acc[i][j] = __builtin_amdgcn_mfma_f32_16x16x32_bf16(al[i], bh[j], acc[i][j], 0, 0, 0);
            }
    }

    float* Cg = C + (long)blockIdx.z * sC + (long)(m0 + wm * 64) * ldc + (n0 + wn * 64);
    const int r4 = (lane >> 4) * 4;
#pragma unroll
    for (int i = 0; i < 4; i++)
#pragma unroll
        for (int j = 0; j < 4; j++) {
            float* cp = Cg + (long)(i * 16 + r4) * ldc + j * 16 + lr;
#pragma unroll
            for (int q = 0; q < 4; q++)
                cp[(long)q * ldc] = acc[i][j][q] * scale;
        }
}

// ---------------------------------------------------------------------------
// Masked softmax over rows of 2048, in place on f32. mask int32 (!=0), coalesced
// int4 reads. att_h (optional): fp16 plane out for phase 4.
// ---------------------------------------------------------------------------
__global__ __launch_bounds__(256) void softmax_rows(
    float* __restrict__ att, const int* __restrict__ mask, u16* __restrict__ att_h)
{
    const int  row  = blockIdx.x;                    // b*512 + k
    const int  tid  = threadIdx.x;
    const long base = (long)row * 2048 + tid * 8;

    f32x4 s0 = *(const f32x4*)(att + base);
    f32x4 s1 = *(const f32x4*)(att + base + 4);
    float x[8] = {s0[0], s0[1], s0[2], s0[3], s1[0], s1[1], s1[2], s1[3]};

    if (mask) {
        int4 mv0 = *(const int4*)(mask + base);
        int4 mv1 = *(const int4*)(mask + base + 4);
        const int mk[8] = {mv0.x, mv0.y, mv0.z, mv0.w, mv1.x, mv1.y, mv1.z, mv1.w};
#pragma unroll
        for (int j = 0; j < 8; j++) x[j] = mk[j] ? x[j] : -INFINITY;
    }

    float mx = x[0];
#pragma unroll
    for (int j = 1; j < 8; j++) mx = fmaxf(mx, x[j]);
#pragma unroll
    for (int off = 32; off > 0; off >>= 1) mx = fmaxf(mx, __shfl_down(mx, off));

    __shared__ float red[8];
    const int wave = tid >> 6, lane = tid & 63;
    if (lane == 0) red[wave] = mx;
    __syncthreads();
    mx = fmaxf(fmaxf(red[0], red[1]), fmaxf(red[2], red[3]));

    if (mx == -INFINITY) {                           // all-masked row: zeros, not NaN
        f32x4 z = {0.f, 0.f, 0.f, 0.f};
        *(f32x4*)(att + base) = z;
        *(f32x4*)(att + base + 4) = z;
        if (att_h) {
            u16x8 zh = {0, 0, 0, 0, 0, 0, 0, 0};
            *(u16x8*)(att_h + base) = zh;
        }
        return;
    }

    float e[8], s = 0.f;
#pragma unroll
    for (int j = 0; j < 8; j++) { e[j] = __expf(x[j] - mx); s += e[j]; }
#pragma unroll
    for (int off = 32; off > 0; off >>= 1) s += __shfl_down(s, off);
    if (lane == 0) red[4 + wave] = s;
    __syncthreads();
    s = red[4] + red[5] + red[6] + red[7];

    const float inv = 1.f / s;
    f32x4 o0, o1;
#pragma unroll
    for (int j = 0; j < 4; j++) { o0[j] = e[j] * inv; o1[j] = e[4 + j] * inv; }
    *(f32x4*)(att + base) = o0;
    *(f32x4*)(att + base + 4) = o1;
    if (att_h) {
        u16x8 hv;
#pragma unroll
        for (int j = 0; j < 4; j++) {
            _Float16 h0 = (_Float16)o0[j];
            _Float16 h1 = (_Float16)o1[j];
            hv[j]     = __builtin_bit_cast(u16, h0);
            hv[4 + j] = __builtin_bit_cast(u16, h1);
        }
        *(u16x8*)(att_h + base) = hv;
    }
}

// ---------------------------------------------------------------------------
extern "C" void kernel_launch(void* const* d_in, const int* in_sizes, int n_in,
                              void* d_out, int out_size, void* d_ws, size_t ws_size,
                              hipStream_t stream)
{
    const float* query = nullptr;   // 512*1024      = 524288
    const float* key   = nullptr;   // 16*2048*1024  = 33554432
    const float* W     = nullptr;   // 1024*1024     = 1048576
    const int*   mask  = nullptr;   // 16*512*2048   = 16777216
    for (int i = 0; i < n_in; i++) {
        switch (in_sizes[i]) {
            case 524288:   query = (const float*)d_in[i]; break;
            case 33554432: key   = (const float*)d_in[i]; break;
            case 1048576:  W     = (const float*)d_in[i]; break;
            case 16777216: mask  = (const int*)d_in[i];   break;
        }
    }

    float* out = (float*)d_out;                     // [16,512,1024] f32
    float* att = out + (long)16 * 512 * 1024;       // [16,512,2048] f32

    // ws layout (bytes): att_h 32M | qW_h 1M | qW_l 1M
    const size_t NEED = (size_t)35651584;           // 34 MiB
    if (ws_size >= NEED) {
        char* w = (char*)d_ws;
        u16* att_h = (u16*)(w);
        u16* qW_h  = (u16*)(w + 33554432);
        u16* qW_l  = (u16*)(w + 34603008);

        // 1) qW = (query @ W)/32 -> fp16 hi/lo planes (128 blocks, ~15us)
        prep_qw<<<dim3(128), 256, 0, stream>>>(query, W, qW_h, qW_l);

        // 2) att_raw = qW @ key^T (2-MFMA; B = f32 key staged directly)
        gemm_s<<<dim3(16, 4, 16), 256, 0, stream>>>(qW_h, qW_l, key, att);

        // 3) masked softmax (coalesced int4 mask), emits fp16 att plane
        softmax_rows<<<dim3(16 * 512), 256, 0, stream>>>(att, mask, att_h);

        // 4) out = att_h @ key (B = f32 key, reg-staged transpose-convert)
        gemm_av<<<dim3(8, 4, 16), 256, 0, stream>>>(att_h, key, out);
    } else {
        // -------- fallback: verified round-1 path (bf16 in-kernel split) --------
        float* qW = out;                            // f32 scratch (dead before phase 4)
        gemm_mfma<false><<<dim3(8, 4, 1), 256, 0, stream>>>(
            query, W, qW, 1024, 1024, 1024, 1024, 0L, 0L, 0L, 1.f / 32.f);
        gemm_mfma<true><<<dim3(16, 4, 16), 256, 0, stream>>>(
            qW, key, att, 1024, 1024, 1024, 2048,
            0L, (long)2048 * 1024, (long)512 * 2048, 1.f);
        softmax_rows<<<dim3(16 * 512), 256, 0, stream>>>(att, mask, nullptr);
        gemm_mfma<false><<<dim3(8, 4, 16), 256, 0, stream>>>(
            att, key, out, 2048, 2048, 1024, 1024,
            (long)512 * 2048, (long)2048 * 1024, (long)512 * 1024, 1.f);
    }
}

// Round 12
// 197.283 us; speedup vs baseline: 1.1180x; 1.1180x over previous
//
#include <hip/hip_runtime.h>

// SimpleConcatAttention on MI355X — round 12: r10 structure restored (keyT in prep
// warms L3 for gemm_s — r11 lesson: removing that read cost gemm_s +25% on cold
// HBM drains) + gemm_s reduced to 1-MFMA (qW hi only; error budget ~sqrt(2)x).
// Inputs: query f32 [512,1024], key f32 [16,2048,1024], W f32 [1024,1024],
// att_mask int32 [16,512,2048]. Outputs (d_out, f32): out [16,512,1024] ++ att [16,512,2048].
// Pipeline (main path, ws >= 97 MiB):
//   prep_all: blocks 0-127 : qW=(q@W)/32 (3-MFMA fp16 internal, 64x64, BK=64,
//             setprio) -> qW_h fp16 plane only
//             blocks 128+ : key f32 -> keyT [d][n] fp16 (t[64*65] two-pass;
//             ALSO acts as L3 prefetch of key for gemm_s)
//   phase2:  att_raw = qW @ key^T (1-MFMA: Ah.B; B = f32 key staged via
//            global_load_lds, 16B-granule XOR, fp16 convert at frag read).
//            LDS 48KB -> 3 blocks/CU (was 2).
//   softmax: masked softmax in place (coalesced int4 mask), emits att_h fp16
//   phase4:  out = att_h @ keyT^T (NT, 1-MFMA fp16, BK=128) — verified 35us
// Fallback (small ws): verified round-1 all-f32-input bf16-split path.

typedef float  f32x4  __attribute__((ext_vector_type(4)));
typedef short  bf16x8 __attribute__((ext_vector_type(8)));
typedef _Float16 f16x8 __attribute__((ext_vector_type(8)));
typedef unsigned short u16;
typedef unsigned short u16x8 __attribute__((ext_vector_type(8)));
typedef unsigned short u16x4 __attribute__((ext_vector_type(4)));

// ---- fp16 split: x = hi + lo, |x-hi-lo| <= 2^-22 |x| ----
__device__ __forceinline__ void split2h(float x, u16& hi, u16& lo)
{
    _Float16 h = (_Float16)x;
    _Float16 l = (_Float16)(x - (float)h);
    hi = __builtin_bit_cast(u16, h);
    lo = __builtin_bit_cast(u16, l);
}

// ---- bf16 split (fallback path) ----
__device__ __forceinline__ void split2(float x, u16& hi, u16& lo)
{
    unsigned u = __float_as_uint(x);
    hi = (u16)(u >> 16);
    float hf = __uint_as_float(u & 0xFFFF0000u);
    float lf = x - hf;
    lo = (u16)(__float_as_uint(lf) >> 16);
}

__device__ __forceinline__ void async_cp16(const void* g, void* l)
{
    __builtin_amdgcn_global_load_lds(
        (const __attribute__((address_space(1))) unsigned int*)g,
        (__attribute__((address_space(3))) unsigned int*)l, 16, 0, 0);
}

// ---------------------------------------------------------------------------
// Phase-2 scores GEMM: att[z] = qW @ key[z]^T.
// A: qW_h fp16 plane [512][1024]; B: key f32 [z][2048][1024].
// 128x128 tile, BK=64, 4 waves 2x2. 1-MFMA: Ah.B (B = fp16(key)).
// B staged as f32 with 16B-granule XOR swizzle; converted at frag read.
// LDS 48KB -> 3 blocks/CU.
// ---------------------------------------------------------------------------
__global__ __launch_bounds__(256, 2) void gemm_s(
    const u16* __restrict__ Ah,
    const float* __restrict__ key, float* __restrict__ C)
{
    __shared__ __attribute__((aligned(16))) unsigned char smem[49152];
    u16*   Ahs = (u16*)smem;                      // [128][64] u16, 16KB
    float* Bfs = (float*)(smem + 16384);          // [128][64] f32, 32KB

    const int tid  = threadIdx.x;
    const int lane = tid & 63;
    const int wid  = tid >> 6;
    const int wm   = wid >> 1, wn = wid & 1;      // 2x2 wave grid, 64x64 each
    const int fr   = lane & 15;                   // frag row/col
    const int fq   = lane >> 4;                   // k-quarter

    const int m0 = blockIdx.y * 128, n0 = blockIdx.x * 128;
    const u16*   Ag = Ah + (long)m0 * 1024;
    const float* Bg = key + (long)blockIdx.z * 2048 * 1024 + (long)n0 * 1024;

    f32x4 acc[4][4];
#pragma unroll
    for (int i = 0; i < 4; i++)
#pragma unroll
        for (int j = 0; j < 4; j++) acc[i][j] = (f32x4){0.f, 0.f, 0.f, 0.f};

    for (int k0 = 0; k0 < 1024; k0 += 64) {
        __syncthreads();                          // prev tile's frag reads done
        // ---- A staging (u16 plane): 16 chunks, octet-XOR (r&7) ----
#pragma unroll
        for (int i = 0; i < 4; i++) {
            const int q   = wid * 4 + i;
            const int p   = q * 512 + lane * 8;   // flat u16 pos
            const int r   = p >> 6;               // row
            const int oct = (p & 63) >> 3;
            const long go = (long)r * 1024 + k0 + ((oct ^ (r & 7)) << 3);
            async_cp16(Ag + go, Ahs + q * 512);
        }
        // ---- B staging (f32): 32 chunks, 16B-granule XOR (r&15) ----
#pragma unroll
        for (int i = 0; i < 8; i++) {
            const int q = wid * 8 + i;
            const int G = q * 64 + lane;          // flat 16B-granule index
            const int r = G >> 4;                 // row (128 rows x 16 granules)
            const int g = G & 15;
            const long go = (long)r * 1024 + k0 + ((g ^ (r & 15)) << 2);
            async_cp16(Bg + go, Bfs + q * 256);
        }
        __syncthreads();                          // compiler drains vmcnt

        // ---- 2 k-steps of 32: frag reads (swizzled) + MFMAs ----
#pragma unroll
        for (int ks = 0; ks < 2; ks++) {
            const int cl = fq + ks * 4;           // 8-elem octet index 0..7
            f16x8 ah[4], bh[4];
#pragma unroll
            for (int i = 0; i < 4; i++) {
                const int ra = wm * 64 + i * 16 + fr;
                const int oa = ra * 64 + ((cl ^ (ra & 7)) << 3);
                ah[i] = *(const f16x8*)&Ahs[oa];
                const int rb = wn * 64 + i * 16 + fr;
                const int g0 = ((2 * cl)     ^ (rb & 15)) << 2;   // f32 col of k..k+3
                const int g1 = ((2 * cl + 1) ^ (rb & 15)) << 2;   // f32 col of k+4..k+7
                f32x4 b0 = *(const f32x4*)&Bfs[rb * 64 + g0];
                f32x4 b1 = *(const f32x4*)&Bfs[rb * 64 + g1];
#pragma unroll
                for (int e = 0; e < 4; e++) {
                    bh[i][e]     = (_Float16)b0[e];
                    bh[i][4 + e] = (_Float16)b1[e];
                }
            }
#pragma unroll
            for (int i = 0; i < 4; i++)
#pragma unroll
                for (int j = 0; j < 4; j++)
                    acc[i][j] = __builtin_amdgcn_mfma_f32_16x16x32_f16(ah[i], bh[j], acc[i][j], 0, 0, 0);
        }
    }

    // ---- epilogue (m89 layout: row = fq*4 + q, col = fr) ----
    float* Cg = C + (long)blockIdx.z * 512 * 2048 + (long)(m0 + wm * 64) * 2048 + (n0 + wn * 64);
    const int r4 = fq * 4;
#pragma unroll
    for (int i = 0; i < 4; i++)
#pragma unroll
        for (int j = 0; j < 4; j++) {
            float* cp = Cg + (long)(i * 16 + r4) * 2048 + j * 16 + fr;
#pragma unroll
            for (int q = 0; q < 4; q++)
                cp[(long)q * 2048] = acc[i][j][q];
        }
}

// ---------------------------------------------------------------------------
// Phase-4 NT fp16 GEMM: C[z] = A[z] @ B[z]^T (1-MFMA), BK=128. (r10-verified)
// ---------------------------------------------------------------------------
__global__ __launch_bounds__(256, 2) void gemm_nt_f16(
    const u16* __restrict__ Ah, const u16* __restrict__ Bh,
    float* __restrict__ C,
    int Kd, long sA, long sB, long sC, int ldc)
{
    constexpr int BK = 128;
    constexpr int PS = 128 * BK;                  // u16 per plane tile
    __shared__ __attribute__((aligned(16))) u16 lds[2 * PS];
    u16* Ahs = lds;
    u16* Bhs = lds + PS;

    const int tid  = threadIdx.x;
    const int lane = tid & 63;
    const int wid  = tid >> 6;
    const int wm   = wid >> 1, wn = wid & 1;
    const int fr   = lane & 15;
    const int fq   = lane >> 4;

    const int m0 = blockIdx.y * 128, n0 = blockIdx.x * 128;
    const u16* Ag = Ah + (long)blockIdx.z * sA + (long)m0 * Kd;
    const u16* Bg = Bh + (long)blockIdx.z * sB + (long)n0 * Kd;

    f32x4 acc[4][4];
#pragma unroll
    for (int i = 0; i < 4; i++)
#pragma unroll
        for (int j = 0; j < 4; j++) acc[i][j] = (f32x4){0.f, 0.f, 0.f, 0.f};

    for (int k0 = 0; k0 < Kd; k0 += BK) {
        __syncthreads();
#pragma unroll
        for (int i = 0; i < 8; i++) {
            const int q   = wid * 8 + i;
            const int p   = q * 512 + lane * 8;
            const int r   = p / BK;
            const int oct = (p & (BK - 1)) >> 3;
            const long go = (long)r * Kd + k0 + ((oct ^ (r & 7)) << 3);
            async_cp16(Ag + go, Ahs + q * 512);
            async_cp16(Bg + go, Bhs + q * 512);
        }
        __syncthreads();

#pragma unroll
        for (int ks = 0; ks < BK / 32; ks++) {
            const int cl = fq + ks * 4;
            f16x8 ah[4], bh[4];
#pragma unroll
            for (int i = 0; i < 4; i++) {
                const int ra = wm * 64 + i * 16 + fr;
                ah[i] = *(const f16x8*)&Ahs[ra * BK + ((cl ^ (ra & 7)) << 3)];
                const int rb = wn * 64 + i * 16 + fr;
                bh[i] = *(const f16x8*)&Bhs[rb * BK + ((cl ^ (rb & 7)) << 3)];
            }
#pragma unroll
            for (int i = 0; i < 4; i++)
#pragma unroll
                for (int j = 0; j < 4; j++)
                    acc[i][j] = __builtin_amdgcn_mfma_f32_16x16x32_f16(ah[i], bh[j], acc[i][j], 0, 0, 0);
        }
    }

    float* Cg = C + (long)blockIdx.z * sC + (long)(m0 + wm * 64) * ldc + (n0 + wn * 64);
    const int r4 = fq * 4;
#pragma unroll
    for (int i = 0; i < 4; i++)
#pragma unroll
        for (int j = 0; j < 4; j++) {
            float* cp = Cg + (long)(i * 16 + r4) * ldc + j * 16 + fr;
#pragma unroll
            for (int q = 0; q < 4; q++)
                cp[(long)q * ldc] = acc[i][j][q];
        }
}

// ---------------------------------------------------------------------------
// prep_all: one dispatch, two roles.
//  blocks 0..127  : qW = (query @ W)/32 (NN, 3-MFMA fp16 internal, 64x64,
//                   BK=64, setprio) -> qW_h fp16 plane (hi only).
//  blocks 128..   : key f32 tile 64x64 -> keyT [d][n] fp16 (r5-verified
//                   t[64*65] two-pass; doubles as L3 prefetch of key).
// ---------------------------------------------------------------------------
__global__ __launch_bounds__(256) void prep_all(
    const float* __restrict__ query, const float* __restrict__ W,
    const float* __restrict__ key,
    u16* __restrict__ qW_h, u16* __restrict__ keyT)
{
    constexpr int LDg = 72;                       // GEMM LDS row stride (u16)
    __shared__ __attribute__((aligned(16))) u16 sm[4 * 64 * LDg];   // 36 KiB union
    const int tid = threadIdx.x;

    if (blockIdx.x >= 128) {
        // ------------- key transpose: f32 [n][d] -> fp16 keyT [d][n] -------------
        u16* t = sm;                              // 64*65 u16 buffer
        const int idx2 = (int)blockIdx.x - 128;
        const int bx = idx2 & 15, by = (idx2 >> 4) & 31, bz = idx2 >> 9;
        const long zin = (long)bz * 2048 * 1024;
        const int n0 = by * 64, d0 = bx * 64;
#pragma unroll
        for (int j = 0; j < 4; j++) {
            const int idx = tid + j * 256;        // 1024 f32x4 chunks
            const int row = idx >> 4;             // n-offset
            const int col = (idx & 15) * 4;       // d-offset
            f32x4 v = *(const f32x4*)(key + zin + (long)(n0 + row) * 1024 + d0 + col);
#pragma unroll
            for (int e = 0; e < 4; e++) {
                _Float16 hh = (_Float16)v[e];
                t[(col + e) * 65 + row] = __builtin_bit_cast(u16, hh);
            }
        }
        __syncthreads();
        const long zT = (long)bz * 1024 * 2048;
#pragma unroll
        for (int j = 0; j < 4; j++) {
            const int idx = tid + j * 256;
            const int dr = idx >> 4;              // d-offset
            const int nc = (idx & 15) * 4;        // n-offset
            u16x4 o = {t[dr * 65 + nc], t[dr * 65 + nc + 1],
                       t[dr * 65 + nc + 2], t[dr * 65 + nc + 3]};
            *(u16x4*)(keyT + zT + (long)(d0 + dr) * 2048 + n0 + nc) = o;
        }
        return;
    }

    // ------------- phase1 qW GEMM (NN, M=512 N=1024 K=1024) -------------
    u16* As_h = sm;                               // [64][72]
    u16* As_l = sm + 64 * LDg;
    u16* Bs_h = sm + 2 * 64 * LDg;
    u16* Bs_l = sm + 3 * 64 * LDg;

    const int lane = tid & 63, wid = tid >> 6;
    const int wm = wid >> 1, wn = wid & 1;        // 2x2 wave grid, 32x32 each
    const int lr = lane & 15, fq = lane >> 4;
    const int m0 = ((int)blockIdx.x >> 4) * 64;   // 8 m-tiles
    const int n0 = ((int)blockIdx.x & 15) * 64;   // 16 n-tiles
    const float* Ag = query + (long)m0 * 1024;
    const float* Bg = W + n0;

    __builtin_amdgcn_s_setprio(1);                // outrank streaming waves

    f32x4 acc[2][2];
#pragma unroll
    for (int i = 0; i < 2; i++)
#pragma unroll
        for (int j = 0; j < 2; j++) acc[i][j] = (f32x4){0.f, 0.f, 0.f, 0.f};

    for (int k0 = 0; k0 < 1024; k0 += 64) {
        __syncthreads();
        // stage A [64 m x 64 k]
        {
            const int row = tid >> 2, kb = (tid & 3) * 16;
            const float* src = Ag + (long)row * 1024 + k0 + kb;
            f32x4 v0 = *(const f32x4*)src;
            f32x4 v1 = *(const f32x4*)(src + 4);
            f32x4 v2 = *(const f32x4*)(src + 8);
            f32x4 v3 = *(const f32x4*)(src + 12);
            u16x8 h0, h1, l0, l1;
#pragma unroll
            for (int e = 0; e < 4; e++) {
                u16 hh, ll;
                split2h(v0[e], hh, ll); h0[e] = hh;     l0[e] = ll;
                split2h(v1[e], hh, ll); h0[4 + e] = hh; l0[4 + e] = ll;
                split2h(v2[e], hh, ll); h1[e] = hh;     l1[e] = ll;
                split2h(v3[e], hh, ll); h1[4 + e] = hh; l1[4 + e] = ll;
            }
            *(u16x8*)&As_h[row * LDg + kb]     = h0;
            *(u16x8*)&As_h[row * LDg + kb + 8] = h1;
            *(u16x8*)&As_l[row * LDg + kb]     = l0;
            *(u16x8*)&As_l[row * LDg + kb + 8] = l1;
        }
        // stage B (W[k][n] 64x64, transpose in regs)
        {
            const int n = lane;
            u16x8 h0, h1, l0, l1;
#pragma unroll
            for (int kk = 0; kk < 8; kk++) {
                float x0 = Bg[(long)(k0 + wid * 16 + kk) * 1024 + n];
                float x1 = Bg[(long)(k0 + wid * 16 + 8 + kk) * 1024 + n];
                u16 hh, ll;
                split2h(x0, hh, ll); h0[kk] = hh; l0[kk] = ll;
                split2h(x1, hh, ll); h1[kk] = hh; l1[kk] = ll;
            }
            *(u16x8*)&Bs_h[n * LDg + wid * 16]     = h0;
            *(u16x8*)&Bs_h[n * LDg + wid * 16 + 8] = h1;
            *(u16x8*)&Bs_l[n * LDg + wid * 16]     = l0;
            *(u16x8*)&Bs_l[n * LDg + wid * 16 + 8] = l1;
        }
        __syncthreads();

#pragma unroll
        for (int ks = 0; ks < 2; ks++) {
            f16x8 ah[2], al[2], bh[2], bl[2];
#pragma unroll
            for (int i = 0; i < 2; i++) {
                const int ra = (wm * 32 + i * 16 + lr) * LDg + ks * 32 + fq * 8;
                ah[i] = *(const f16x8*)&As_h[ra];
                al[i] = *(const f16x8*)&As_l[ra];
                const int rb = (wn * 32 + i * 16 + lr) * LDg + ks * 32 + fq * 8;
                bh[i] = *(const f16x8*)&Bs_h[rb];
                bl[i] = *(const f16x8*)&Bs_l[rb];
            }
#pragma unroll
            for (int i = 0; i < 2; i++)
#pragma unroll
                for (int j = 0; j < 2; j++) {
                    acc[i][j] = __builtin_amdgcn_mfma_f32_16x16x32_f16(ah[i], bh[j], acc[i][j], 0, 0, 0);
                    acc[i][j] = __builtin_amdgcn_mfma_f32_16x16x32_f16(ah[i], bl[j], acc[i][j], 0, 0, 0);
                    acc[i][j] = __builtin_amdgcn_mfma_f32_16x16x32_f16(al[i], bh[j], acc[i][j], 0, 0, 0);
                }
        }
    }

    __builtin_amdgcn_s_setprio(0);

    // epilogue: scale -> fp16 hi plane (lo not needed: gemm_s is 1-MFMA now)
    const int r4 = fq * 4;
#pragma unroll
    for (int i = 0; i < 2; i++)
#pragma unroll
        for (int j = 0; j < 2; j++)
#pragma unroll
            for (int q = 0; q < 4; q++) {
                float v = acc[i][j][q] * (1.f / 32.f);
                _Float16 hh = (_Float16)v;
                const long o = (long)(m0 + wm * 32 + i * 16 + r4 + q) * 1024
                             + n0 + wn * 32 + j * 16 + lr;
                qW_h[o] = __builtin_bit_cast(u16, hh);
            }
}

// ---------------------------------------------------------------------------
// Round-1 f32 MFMA GEMM (fallback path only).
// ---------------------------------------------------------------------------
template<bool BT>
__global__ __launch_bounds__(256, 2) void gemm_mfma(
    const float* __restrict__ A, const float* __restrict__ B,
    float* __restrict__ C,
    int Kd, int lda, int ldb, int ldc,
    long sA, long sB, long sC, float scale)
{
    constexpr int LD = 40;
    __shared__ __attribute__((aligned(16))) u16 As_hi[128 * LD];
    __shared__ __attribute__((aligned(16))) u16 As_lo[128 * LD];
    __shared__ __attribute__((aligned(16))) u16 Bs_hi[128 * LD];
    __shared__ __attribute__((aligned(16))) u16 Bs_lo[128 * LD];

    const int tid  = threadIdx.x;
    const int lane = tid & 63;
    const int wid  = tid >> 6;
    const int wm   = wid >> 1, wn = wid & 1;
    const int lr   = lane & 15;
    const int lk   = (lane >> 4) * 8;

    const int m0 = blockIdx.y * 128, n0 = blockIdx.x * 128;
    const float* Ag = A + (long)blockIdx.z * sA + (long)m0 * lda;
    const float* Bg = B + (long)blockIdx.z * sB + (BT ? (long)n0 * ldb : (long)n0);

    f32x4 acc[4][4];
#pragma unroll
    for (int i = 0; i < 4; i++)
#pragma unroll
        for (int j = 0; j < 4; j++) acc[i][j] = (f32x4){0.f, 0.f, 0.f, 0.f};

    for (int k0 = 0; k0 < Kd; k0 += 32) {
        __syncthreads();
#pragma unroll
        for (int it = 0; it < 2; it++) {
            const int p   = tid + it * 256;
            const int row = p >> 2, k8 = (p & 3) * 8;
            const float* src = Ag + (long)row * lda + k0 + k8;
            f32x4 v0 = *(const f32x4*)src;
            f32x4 v1 = *(const f32x4*)(src + 4);
            u16x8 h, l;
#pragma unroll
            for (int e = 0; e < 4; e++) {
                u16 hh, ll;
                split2(v0[e], hh, ll); h[e] = hh;     l[e] = ll;
                split2(v1[e], hh, ll); h[4 + e] = hh; l[4 + e] = ll;
            }
            *(u16x8*)&As_hi[row * LD + k8] = h;
            *(u16x8*)&As_lo[row * LD + k8] = l;
        }
        if constexpr (BT) {
#pragma unroll
            for (int it = 0; it < 2; it++) {
                const int p   = tid + it * 256;
                const int row = p >> 2, k8 = (p & 3) * 8;
                const float* src = Bg + (long)row * ldb + k0 + k8;
                f32x4 v0 = *(const f32x4*)src;
                f32x4 v1 = *(const f32x4*)(src + 4);
                u16x8 h, l;
#pragma unroll
                for (int e = 0; e < 4; e++) {
                    u16 hh, ll;
                    split2(v0[e], hh, ll); h[e] = hh;     l[e] = ll;
                    split2(v1[e], hh, ll); h[4 + e] = hh; l[4 + e] = ll;
                }
                *(u16x8*)&Bs_hi[row * LD + k8] = h;
                *(u16x8*)&Bs_lo[row * LD + k8] = l;
            }
        } else {
#pragma unroll
            for (int h2 = 0; h2 < 2; h2++) {
                const int n = h2 * 64 + lane;
                u16x8 h, l;
#pragma unroll
                for (int kk = 0; kk < 8; kk++) {
                    float x = Bg[(long)(k0 + wid * 8 + kk) * ldb + n];
                    u16 hh, ll;
                    split2(x, hh, ll);
                    h[kk] = hh; l[kk] = ll;
                }
                *(u16x8*)&Bs_hi[n * LD + wid * 8] = h;
                *(u16x8*)&Bs_lo[n * LD + wid * 8] = l;
            }
        }
        __syncthreads();

        bf16x8 ah[4], al[4], bh[4], bl[4];
#pragma unroll
        for (int i = 0; i < 4; i++) {
            const int ra = (wm * 64 + i * 16 + lr) * LD + lk;
            ah[i] = *(const bf16x8*)&As_hi[ra];
            al[i] = *(const bf16x8*)&As_lo[ra];
            const int rb = (wn * 64 + i * 16 + lr) * LD + lk;
            bh[i] = *(const bf16x8*)&Bs_hi[rb];
            bl[i] = *(const bf16x8*)&Bs_lo[rb];
        }
#pragma unroll
        for (int i = 0; i < 4; i++)
#pragma unroll
            for (int j = 0; j < 4; j++) {
                acc[i][j] = __builtin_amdgcn_mfma_f32_16x16x32_bf16(ah[i], bh[j], acc[i][j], 0, 0, 0);
                acc[i][j] = __builtin_amdgcn_mfma_f32_16x16x32_bf16(ah[i], bl[j], acc[i][j], 0, 0, 0);
                acc[i][j] = __builtin_amdgcn_mfma_f32_16x16x32_bf16(al[i], bh[j], acc[i][j], 0, 0, 0);
            }
    }

    float* Cg = C + (long)blockIdx.z * sC + (long)(m0 + wm * 64) * ldc + (n0 + wn * 64);
    const int r4 = (lane >> 4) * 4;
#pragma unroll
    for (int i = 0; i < 4; i++)
#pragma unroll
        for (int j = 0; j < 4; j++) {
            float* cp = Cg + (long)(i * 16 + r4) * ldc + j * 16 + lr;
#pragma unroll
            for (int q = 0; q < 4; q++)
                cp[(long)q * ldc] = acc[i][j][q] * scale;
        }
}

// ---------------------------------------------------------------------------
// Masked softmax over rows of 2048, in place on f32. mask int32 (!=0), coalesced
// int4 reads. att_h (optional): fp16 plane out for phase 4.
// ---------------------------------------------------------------------------
__global__ __launch_bounds__(256) void softmax_rows(
    float* __restrict__ att, const int* __restrict__ mask, u16* __restrict__ att_h)
{
    const int  row  = blockIdx.x;                    // b*512 + k
    const int  tid  = threadIdx.x;
    const long base = (long)row * 2048 + tid * 8;

    f32x4 s0 = *(const f32x4*)(att + base);
    f32x4 s1 = *(const f32x4*)(att + base + 4);
    float x[8] = {s0[0], s0[1], s0[2], s0[3], s1[0], s1[1], s1[2], s1[3]};

    if (mask) {
        int4 mv0 = *(const int4*)(mask + base);
        int4 mv1 = *(const int4*)(mask + base + 4);
        const int mk[8] = {mv0.x, mv0.y, mv0.z, mv0.w, mv1.x, mv1.y, mv1.z, mv1.w};
#pragma unroll
        for (int j = 0; j < 8; j++) x[j] = mk[j] ? x[j] : -INFINITY;
    }

    float mx = x[0];
#pragma unroll
    for (int j = 1; j < 8; j++) mx = fmaxf(mx, x[j]);
#pragma unroll
    for (int off = 32; off > 0; off >>= 1) mx = fmaxf(mx, __shfl_down(mx, off));

    __shared__ float red[8];
    const int wave = tid >> 6, lane = tid & 63;
    if (lane == 0) red[wave] = mx;
    __syncthreads();
    mx = fmaxf(fmaxf(red[0], red[1]), fmaxf(red[2], red[3]));

    if (mx == -INFINITY) {                           // all-masked row: zeros, not NaN
        f32x4 z = {0.f, 0.f, 0.f, 0.f};
        *(f32x4*)(att + base) = z;
        *(f32x4*)(att + base + 4) = z;
        if (att_h) {
            u16x8 zh = {0, 0, 0, 0, 0, 0, 0, 0};
            *(u16x8*)(att_h + base) = zh;
        }
        return;
    }

    float e[8], s = 0.f;
#pragma unroll
    for (int j = 0; j < 8; j++) { e[j] = __expf(x[j] - mx); s += e[j]; }
#pragma unroll
    for (int off = 32; off > 0; off >>= 1) s += __shfl_down(s, off);
    if (lane == 0) red[4 + wave] = s;
    __syncthreads();
    s = red[4] + red[5] + red[6] + red[7];

    const float inv = 1.f / s;
    f32x4 o0, o1;
#pragma unroll
    for (int j = 0; j < 4; j++) { o0[j] = e[j] * inv; o1[j] = e[4 + j] * inv; }
    *(f32x4*)(att + base) = o0;
    *(f32x4*)(att + base + 4) = o1;
    if (att_h) {
        u16x8 hv;
#pragma unroll
        for (int j = 0; j < 4; j++) {
            _Float16 h0 = (_Float16)o0[j];
            _Float16 h1 = (_Float16)o1[j];
            hv[j]     = __builtin_bit_cast(u16, h0);
            hv[4 + j] = __builtin_bit_cast(u16, h1);
        }
        *(u16x8*)(att_h + base) = hv;
    }
}

// ---------------------------------------------------------------------------
extern "C" void kernel_launch(void* const* d_in, const int* in_sizes, int n_in,
                              void* d_out, int out_size, void* d_ws, size_t ws_size,
                              hipStream_t stream)
{
    const float* query = nullptr;   // 512*1024      = 524288
    const float* key   = nullptr;   // 16*2048*1024  = 33554432
    const float* W     = nullptr;   // 1024*1024     = 1048576
    const int*   mask  = nullptr;   // 16*512*2048   = 16777216
    for (int i = 0; i < n_in; i++) {
        switch (in_sizes[i]) {
            case 524288:   query = (const float*)d_in[i]; break;
            case 33554432: key   = (const float*)d_in[i]; break;
            case 1048576:  W     = (const float*)d_in[i]; break;
            case 16777216: mask  = (const int*)d_in[i];   break;
        }
    }

    float* out = (float*)d_out;                     // [16,512,1024] f32
    float* att = out + (long)16 * 512 * 1024;       // [16,512,2048] f32

    // ws layout (bytes): keyT 64M | att_h 32M | qW_h 1M
    const size_t NEED = (size_t)101711872;          // 97 MiB
    if (ws_size >= NEED) {
        char* w = (char*)d_ws;
        u16* keyT  = (u16*)(w);
        u16* att_h = (u16*)(w + 67108864);
        u16* qW_h  = (u16*)(w + 100663296);

        // 0+1) fused: qW GEMM (blocks 0-127, setprio'd) || key f32 -> keyT fp16
        //      (transpose role also leaves key L3-warm for gemm_s — r11 lesson)
        prep_all<<<dim3(128 + 8192), 256, 0, stream>>>(
            query, W, key, qW_h, keyT);

        // 2) att_raw = qW @ key^T (1-MFMA; B = f32 key staged directly)
        gemm_s<<<dim3(16, 4, 16), 256, 0, stream>>>(qW_h, key, att);

        // 3) masked softmax (coalesced int4 mask), emits fp16 att plane
        softmax_rows<<<dim3(16 * 512), 256, 0, stream>>>(att, mask, att_h);

        // 4) out = att_h @ keyT^T (NT, 1-MFMA fp16, BK=128)
        gemm_nt_f16<<<dim3(8, 4, 16), 256, 0, stream>>>(
            att_h, keyT, out,
            2048, (long)512 * 2048, (long)1024 * 2048, (long)512 * 1024, 1024);
    } else {
        // -------- fallback: verified round-1 path (bf16 in-kernel split) --------
        float* qW = out;                            // f32 scratch (dead before phase 4)
        gemm_mfma<false><<<dim3(8, 4, 1), 256, 0, stream>>>(
            query, W, qW, 1024, 1024, 1024, 1024, 0L, 0L, 0L, 1.f / 32.f);
        gemm_mfma<true><<<dim3(16, 4, 16), 256, 0, stream>>>(
            qW, key, att, 1024, 1024, 1024, 2048,
            0L, (long)2048 * 1024, (long)512 * 2048, 1.f);
        softmax_rows<<<dim3(16 * 512), 256, 0, stream>>>(att, mask, nullptr);
        gemm_mfma<false><<<dim3(8, 4, 16), 256, 0, stream>>>(
            att, key, out, 2048, 2048, 1024, 1024,
            (long)512 * 2048, (long)2048 * 1024, (long)512 * 1024, 1.f);
    }
}